// Round 5
// baseline (357.908 us; speedup 1.0000x reference)
//
#include <hip/hip_runtime.h>

#define D_   64
#define CH   16      // chunk width (columns factored per phase)
#define NBT_ 12800   // B*T = 32*400
#define B_   32

// Broadcast lane l's value of v to all lanes (SGPR result).
__device__ __forceinline__ float rl(float v, int l) {
    return __uint_as_float(__builtin_amdgcn_readlane(__float_as_uint(v), l));
}

// Chunked LEFT-LOOKING Cholesky, one wave per 64x64 matrix, lane = row.
//
// R1-R4 post-mortem: holding the full row (64 VGPRs) + working set always
// exceeds the backend's arch-VGPR target (64-84 regardless of
// launch_bounds / waves_per_eu hints) -> ~30 values spilled to scratch,
// doubling VALU issue (18.7k cyc/wave measured vs 9.4k clean floor) and
// writing 20-100 MB to HBM. Fix: never hold more than 2 chunks of 16.
//
//   for t in 0..3:
//     load cols [16t,16t+16) of this lane's row into cur[16]
//     for m < t: stream retired chunk m from LDS into tmp[16];
//                cur[c] -= tmp[k] * rl(tmp[k], 16t+c)     (rank-16 apply)
//     factor cur[] right-looking (16 steps, fwd-sub + logdet fused)
//     retire cur[] to LDS (chunk 3 never retired)
//
// LDS is PER-LANE PRIVATE scratch (lane j only re-reads lds[..][j];
// broadcasts go through readlane of the streamed registers) -> no
// __syncthreads anywhere. Column-major layout: lane-stride 1 -> 2-way
// bank aliasing = free. Peak live set: cur16 + tmp16 + ~14 = ~46 VGPRs.
__global__ __launch_bounds__(256) void chol_ll(const float* __restrict__ x,
                                               const float* __restrict__ mu,
                                               const float* __restrict__ sigma,
                                               float* __restrict__ partial) {
    __shared__ float lds[4][3][CH][D_];   // 4 waves x 3 retired chunks = 48 KB
    const int lane = threadIdx.x & 63;
    const int wv   = threadIdx.x >> 6;
    const int bt   = blockIdx.x * 4 + wv;

    const float* base = sigma + (size_t)bt * (D_ * D_) + (size_t)lane * D_;
    float d = x[bt * D_ + lane] - mu[bt * D_ + lane];
    float q = 0.f, lg = 0.f;

    #pragma unroll
    for (int t = 0; t < 4; ++t) {
        // ---- load chunk t: 16 contiguous floats of this lane's row ----
        float cur[CH];
        const float4* p = (const float4*)(base + t * CH);
        #pragma unroll
        for (int r = 0; r < 4; ++r) {
            float4 v = p[r];
            cur[4 * r + 0] = v.x; cur[4 * r + 1] = v.y;
            cur[4 * r + 2] = v.z; cur[4 * r + 3] = v.w;
        }
        // ---- apply retired chunks m < t (rank-16 updates) ----
        #pragma unroll
        for (int m = 0; m < t; ++m) {
            float tmp[CH];
            #pragma unroll
            for (int k = 0; k < CH; ++k) tmp[k] = lds[wv][m][k][lane];
            #pragma unroll
            for (int k = 0; k < CH; ++k) {
                #pragma unroll
                for (int c = 0; c < CH; ++c)
                    cur[c] = __builtin_fmaf(-tmp[k], rl(tmp[k], t * CH + c), cur[c]);
            }
        }
        // ---- factor chunk t (right-looking within chunk) ----
        #pragma unroll
        for (int kk = 0; kk < CH; ++kk) {
            const int gk = t * CH + kk;              // global column = pivot row
            float s   = rl(cur[kk], gk) + 1e-6f;     // updated diag + EPS
            float inv = __builtin_amdgcn_rsqf(s);    // 1/L[gk][gk]
            lg += __builtin_amdgcn_logf(s);          // log2(s); scaled at end
            cur[kk] *= inv;                          // L[lane][gk], lanes >= gk
            float zk = rl(d, gk) * inv;              // forward substitution
            q += zk * zk;
            d = __builtin_fmaf(-cur[kk], zk, d);
            #pragma unroll
            for (int c = kk + 1; c < CH; ++c)
                cur[c] = __builtin_fmaf(-cur[kk], rl(cur[kk], t * CH + c), cur[c]);
        }
        // ---- retire chunk t to LDS (not needed for the last chunk) ----
        if (t < 3) {
            #pragma unroll
            for (int c = 0; c < CH; ++c) lds[wv][t][c][lane] = cur[c];
        }
    }

    if (lane == 0) {
        float log_det = 0.34657359027997264f * lg;   // 0.5 * ln2 * sum(log2 s)
        float lp = -0.5f * q - log_det - 58.81206612509905f;  // -0.5*D*ln(2pi)
        partial[bt] = lp;
    }
}

__global__ __launch_bounds__(1024) void reduce_ll(const float* __restrict__ partial,
                                                  float* __restrict__ out) {
    float s = 0.f;
    for (int i = threadIdx.x; i < NBT_; i += 1024) s += partial[i];
    #pragma unroll
    for (int off = 32; off > 0; off >>= 1) s += __shfl_down(s, off, 64);
    __shared__ float ws[16];
    const int lane = threadIdx.x & 63, w = threadIdx.x >> 6;
    if (lane == 0) ws[w] = s;
    __syncthreads();
    if (threadIdx.x == 0) {
        float t = 0.f;
        #pragma unroll
        for (int i = 0; i < 16; ++i) t += ws[i];
        out[0] = -t / (float)B_;   // out = -mean_b sum_t log_prob
    }
}

extern "C" void kernel_launch(void* const* d_in, const int* in_sizes, int n_in,
                              void* d_out, int out_size, void* d_ws, size_t ws_size,
                              hipStream_t stream) {
    const float* x     = (const float*)d_in[0];
    const float* mu    = (const float*)d_in[1];
    const float* sigma = (const float*)d_in[2];
    float* partial = (float*)d_ws;   // NBT_ floats = 51.2 KB scratch
    chol_ll<<<NBT_ / 4, 256, 0, stream>>>(x, mu, sigma, partial);
    reduce_ll<<<1, 1024, 0, stream>>>(partial, (float*)d_out);
}